// Round 1
// baseline (105.429 us; speedup 1.0000x reference)
//
#include <hip/hip_runtime.h>

#define NUM_CLASSES 32
#define NBINS (NUM_CLASSES * NUM_CLASSES)

// Per-batch workspace layout: [hist_in(32), hist_tg(32), inter(32)] uint32
__global__ void dice_hist_kernel(const int* __restrict__ in,
                                 const int* __restrict__ tg,
                                 unsigned int* __restrict__ ws,
                                 long long nPerB) {
    const int b = blockIdx.y;
    __shared__ unsigned int h[NBINS];
    for (int i = threadIdx.x; i < NBINS; i += blockDim.x) h[i] = 0u;
    __syncthreads();

    const long long base = (long long)b * nPerB;
    const int4* in4 = (const int4*)(in + base);
    const int4* tg4 = (const int4*)(tg + base);
    const long long n4 = nPerB >> 2;
    const long long stride = (long long)gridDim.x * blockDim.x;

    for (long long i = (long long)blockIdx.x * blockDim.x + threadIdx.x;
         i < n4; i += stride) {
        int4 a = in4[i];
        int4 t = tg4[i];
        atomicAdd(&h[((a.x & 31) << 5) | (t.x & 31)], 1u);
        atomicAdd(&h[((a.y & 31) << 5) | (t.y & 31)], 1u);
        atomicAdd(&h[((a.z & 31) << 5) | (t.z & 31)], 1u);
        atomicAdd(&h[((a.w & 31) << 5) | (t.w & 31)], 1u);
    }
    __syncthreads();

    // Reduce 2-D histogram -> 96 per-batch counters.
    unsigned int* wsb = ws + b * 96;
    const int t = threadIdx.x;
    if (t < 32) {                       // hist_in[c] = sum_k h[c][k]
        unsigned int s = 0;
        #pragma unroll
        for (int k = 0; k < 32; ++k) s += h[(t << 5) | k];
        atomicAdd(&wsb[t], s);
    } else if (t < 64) {                // hist_tg[c] = sum_k h[k][c]
        const int c = t - 32;
        unsigned int s = 0;
        #pragma unroll
        for (int k = 0; k < 32; ++k) s += h[(k << 5) | c];
        atomicAdd(&wsb[32 + c], s);
    } else if (t < 96) {                // inter[c] = h[c][c]
        const int c = t - 64;
        atomicAdd(&wsb[64 + c], h[(c << 5) | c]);
    }
}

__global__ void dice_final_kernel(const unsigned int* __restrict__ ws,
                                  const float* __restrict__ smooth_p,
                                  float* __restrict__ out, int B) {
    const double s = (double)smooth_p[0];
    const int lane = threadIdx.x;  // 64 threads, 1 block, 1 wave
    double acc = 0.0;
    for (int idx = lane; idx < B * 32; idx += 64) {
        const int b = idx >> 5, c = idx & 31;
        const unsigned int* wsb = ws + b * 96;
        const double inter = (double)wsb[64 + c];
        const double total = (double)wsb[c] + (double)wsb[32 + c];
        acc += 1.0 - (2.0 * inter + s) / (total + s);
    }
    #pragma unroll
    for (int off = 32; off > 0; off >>= 1) acc += __shfl_down(acc, off);
    if (lane == 0) out[0] = (float)(acc / (double)B);
}

extern "C" void kernel_launch(void* const* d_in, const int* in_sizes, int n_in,
                              void* d_out, int out_size, void* d_ws, size_t ws_size,
                              hipStream_t stream) {
    const int* in = (const int*)d_in[0];
    const int* tg = (const int*)d_in[1];
    const float* smooth = (const float*)d_in[2];
    float* out = (float*)d_out;

    const int B = 4;
    const long long total = (long long)in_sizes[0];
    const long long nPerB = total / B;

    // Zero the 96-per-batch counters every call (harness poisons ws once).
    hipMemsetAsync(d_ws, 0, (size_t)(B * 96) * sizeof(unsigned int), stream);

    dim3 grid(256, B);
    dice_hist_kernel<<<grid, dim3(256), 0, stream>>>(in, tg, (unsigned int*)d_ws, nPerB);
    dice_final_kernel<<<1, 64, 0, stream>>>((const unsigned int*)d_ws, smooth, out, B);
}

// Round 3
// 96.357 us; speedup vs baseline: 1.0941x; 1.0941x over previous
//
#include <hip/hip_runtime.h>

#define NUM_CLASSES 32
#define NBINS (NUM_CLASSES * NUM_CLASSES)

typedef int v4i __attribute__((ext_vector_type(4)));  // plain vector: nontemporal-load OK

// Per-batch workspace layout: [hist_in(32), hist_tg(32), inter(32)] uint32
__global__ void __launch_bounds__(256, 8)
dice_hist_kernel(const int* __restrict__ in,
                 const int* __restrict__ tg,
                 unsigned int* __restrict__ ws,
                 long long nPerB) {
    const int b = blockIdx.y;
    __shared__ unsigned int h[NBINS];
    for (int i = threadIdx.x; i < NBINS; i += blockDim.x) h[i] = 0u;
    __syncthreads();

    const long long base = (long long)b * nPerB;
    const v4i* in4 = (const v4i*)(in + base);
    const v4i* tg4 = (const v4i*)(tg + base);
    const long long n4 = nPerB >> 2;
    const long long stride = (long long)gridDim.x * blockDim.x;

    long long i = (long long)blockIdx.x * blockDim.x + threadIdx.x;

    // Unrolled by 2: issue all 4 loads (64B of A + 64B of T in flight)
    // before any LDS atomic, to maximize memory-level parallelism.
    for (; i + stride < n4; i += 2 * stride) {
        v4i a0 = __builtin_nontemporal_load(&in4[i]);
        v4i t0 = __builtin_nontemporal_load(&tg4[i]);
        v4i a1 = __builtin_nontemporal_load(&in4[i + stride]);
        v4i t1 = __builtin_nontemporal_load(&tg4[i + stride]);
        atomicAdd(&h[((a0.x & 31) << 5) | (t0.x & 31)], 1u);
        atomicAdd(&h[((a0.y & 31) << 5) | (t0.y & 31)], 1u);
        atomicAdd(&h[((a0.z & 31) << 5) | (t0.z & 31)], 1u);
        atomicAdd(&h[((a0.w & 31) << 5) | (t0.w & 31)], 1u);
        atomicAdd(&h[((a1.x & 31) << 5) | (t1.x & 31)], 1u);
        atomicAdd(&h[((a1.y & 31) << 5) | (t1.y & 31)], 1u);
        atomicAdd(&h[((a1.z & 31) << 5) | (t1.z & 31)], 1u);
        atomicAdd(&h[((a1.w & 31) << 5) | (t1.w & 31)], 1u);
    }
    for (; i < n4; i += stride) {
        v4i a = __builtin_nontemporal_load(&in4[i]);
        v4i t = __builtin_nontemporal_load(&tg4[i]);
        atomicAdd(&h[((a.x & 31) << 5) | (t.x & 31)], 1u);
        atomicAdd(&h[((a.y & 31) << 5) | (t.y & 31)], 1u);
        atomicAdd(&h[((a.z & 31) << 5) | (t.z & 31)], 1u);
        atomicAdd(&h[((a.w & 31) << 5) | (t.w & 31)], 1u);
    }
    __syncthreads();

    // Reduce 2-D histogram -> 96 per-batch counters.
    unsigned int* wsb = ws + b * 96;
    const int t = threadIdx.x;
    if (t < 32) {                       // hist_in[c] = sum_k h[c][k]
        unsigned int s = 0;
        #pragma unroll
        for (int k = 0; k < 32; ++k) s += h[(t << 5) | k];
        atomicAdd(&wsb[t], s);
    } else if (t < 64) {                // hist_tg[c] = sum_k h[k][c]
        const int c = t - 32;
        unsigned int s = 0;
        #pragma unroll
        for (int k = 0; k < 32; ++k) s += h[(k << 5) | c];
        atomicAdd(&wsb[32 + c], s);
    } else if (t < 96) {                // inter[c] = h[c][c]
        const int c = t - 64;
        atomicAdd(&wsb[64 + c], h[(c << 5) | c]);
    }
}

__global__ void dice_final_kernel(const unsigned int* __restrict__ ws,
                                  const float* __restrict__ smooth_p,
                                  float* __restrict__ out, int B) {
    const double s = (double)smooth_p[0];
    const int lane = threadIdx.x;  // 64 threads, 1 block, 1 wave
    double acc = 0.0;
    for (int idx = lane; idx < B * 32; idx += 64) {
        const int b = idx >> 5, c = idx & 31;
        const unsigned int* wsb = ws + b * 96;
        const double inter = (double)wsb[64 + c];
        const double total = (double)wsb[c] + (double)wsb[32 + c];
        acc += 1.0 - (2.0 * inter + s) / (total + s);
    }
    #pragma unroll
    for (int off = 32; off > 0; off >>= 1) acc += __shfl_down(acc, off);
    if (lane == 0) out[0] = (float)(acc / (double)B);
}

extern "C" void kernel_launch(void* const* d_in, const int* in_sizes, int n_in,
                              void* d_out, int out_size, void* d_ws, size_t ws_size,
                              hipStream_t stream) {
    const int* in = (const int*)d_in[0];
    const int* tg = (const int*)d_in[1];
    const float* smooth = (const float*)d_in[2];
    float* out = (float*)d_out;

    const int B = 4;
    const long long total = (long long)in_sizes[0];
    const long long nPerB = total / B;

    // Zero the 96-per-batch counters every call (harness poisons ws once).
    (void)hipMemsetAsync(d_ws, 0, (size_t)(B * 96) * sizeof(unsigned int), stream);

    dim3 grid(512, B);
    dice_hist_kernel<<<grid, dim3(256), 0, stream>>>(in, tg, (unsigned int*)d_ws, nPerB);
    dice_final_kernel<<<1, 64, 0, stream>>>((const unsigned int*)d_ws, smooth, out, B);
}